// Round 12
// baseline (728.273 us; speedup 1.0000x reference)
//
#include <hip/hip_runtime.h>
#include <hip/hip_bf16.h>
#include <stdint.h>

typedef unsigned short u16;
typedef unsigned int u32;
typedef __attribute__((ext_vector_type(4))) float f32x4;
typedef __attribute__((ext_vector_type(4))) int i32x4;
typedef __attribute__((ext_vector_type(8))) u16 u16x8;
typedef __attribute__((ext_vector_type(8))) __bf16 bf16x8;

constexpr int BATCH = 4096, DIN = 1024, DH = 4096, DOUT = 1024, NEXP = 8;
constexpr int HS_CAP = 2816;  // per-expert row capacity (mean 2560, +8.2 sigma)

struct Ptr4 { float* p[4]; };

__device__ __forceinline__ u16 f2bf(float f) {
  u32 u = __float_as_uint(f);
  u += 0x7fffu + ((u >> 16) & 1u);   // RNE (finite values only here)
  return (u16)(u >> 16);
}

// global -> LDS direct copy, 16B per lane. LDS dest is wave-uniform base;
// HW adds lane*16.
#define GLOAD_LDS16(gp, lp)                                                    \
  __builtin_amdgcn_global_load_lds(                                           \
      (__attribute__((address_space(1))) void*)(gp),                          \
      (__attribute__((address_space(3))) void*)(lp), 16, 0, 0)

#define BAR()                                                                  \
  { asm volatile("" ::: "memory"); __builtin_amdgcn_s_barrier();               \
    asm volatile("" ::: "memory"); }
#define VM4() asm volatile("s_waitcnt vmcnt(4)" ::: "memory")
#define VM0() asm volatile("s_waitcnt vmcnt(0)" ::: "memory")

// stage 128 rows (two 64-row groups via row-base pointers q0,q1)
#define STG4(q0, q1, kofs, dst)                                                \
  { GLOAD_LDS16((q0) + (kofs), (dst));                                         \
    GLOAD_LDS16((q1) + (kofs), (dst) + 4096); }

// ---------------------------------------------------------------------------
// Gate: scores = (x @ gate_w + gate_b)/e, softmax, top-5 mask, renorm.
__global__ void gate_kernel(const float* __restrict__ x,
                            const float* __restrict__ gw,
                            const float* __restrict__ gb,
                            float* __restrict__ wgt) {
  const int wave = threadIdx.x >> 6, lane = threadIdx.x & 63;
  const int b = blockIdx.x * 4 + wave;
  const float* xr = x + (size_t)b * DIN;
  float acc[NEXP];
#pragma unroll
  for (int e = 0; e < NEXP; ++e) acc[e] = 0.f;
  for (int k = lane; k < DIN; k += 64) {
    const float xv = xr[k];
    const f32x4 g0 = *(const f32x4*)(gw + (size_t)k * NEXP);
    const f32x4 g1 = *(const f32x4*)(gw + (size_t)k * NEXP + 4);
    acc[0] += xv * g0[0]; acc[1] += xv * g0[1];
    acc[2] += xv * g0[2]; acc[3] += xv * g0[3];
    acc[4] += xv * g1[0]; acc[5] += xv * g1[1];
    acc[6] += xv * g1[2]; acc[7] += xv * g1[3];
  }
#pragma unroll
  for (int off = 32; off; off >>= 1)
#pragma unroll
    for (int e = 0; e < NEXP; ++e) acc[e] += __shfl_xor(acc[e], off);
  if (lane == 0) {
    const float invT = 0.36787944117144233f;  // 1/e
    float s[NEXP], mx = -1e30f;
    for (int e = 0; e < NEXP; ++e) { s[e] = (acc[e] + gb[e]) * invT; mx = fmaxf(mx, s[e]); }
    float p[NEXP], sum = 0.f;
    for (int e = 0; e < NEXP; ++e) { p[e] = expf(s[e] - mx); sum += p[e]; }
    const float inv = 1.f / sum;
    for (int e = 0; e < NEXP; ++e) p[e] *= inv;
    float w[NEXP], wsum = 0.f;
    for (int e = 0; e < NEXP; ++e) {
      int cnt = 0;
      for (int j = 0; j < NEXP; ++j) cnt += (p[j] > p[e]) || (p[j] == p[e] && j < e);
      w[e] = (cnt < 5) ? p[e] : 0.f;   // top-5 of 8
      wsum += w[e];
    }
    const float inv2 = 1.f / (wsum + 1e-8f);
    for (int e = 0; e < NEXP; ++e) wgt[(size_t)b * NEXP + e] = w[e] * inv2;
  }
}

// ---------------------------------------------------------------------------
// Per-expert row compaction. Position order is atomic-order-dependent but the
// OUTPUT is permutation-invariant (each row's result depends only on itself).
__global__ void assign_kernel(const float* __restrict__ wgt,
                              int* __restrict__ cnt, u16* __restrict__ ridx) {
  const int b = blockIdx.x * 256 + threadIdx.x;
#pragma unroll
  for (int e = 0; e < NEXP; ++e) {
    if (wgt[(size_t)b * NEXP + e] != 0.f) {
      const int pos = atomicAdd(&cnt[e], 1);
      if (pos < BATCH) ridx[e * BATCH + pos] = (u16)b;
    }
  }
}

// ---------------------------------------------------------------------------
// Build L1 work-list: items in (e, n, m) order so consecutive items share the
// (e,n) B-panel; persistent blocks take contiguous ranges -> B reused from L2.
__global__ void build_items(const int* __restrict__ cnt,
                            u32* __restrict__ items, int* __restrict__ itot) {
  if (threadIdx.x != 0) return;
  int t = 0;
  for (int e = 0; e < NEXP; ++e) {
    int c = cnt[e]; c = c < HS_CAP ? c : HS_CAP;
    const int nm = (c + 255) >> 8;
    for (int n = 0; n < DH / 256; ++n)
      for (int m = 0; m < nm; ++m)
        items[t++] = ((u32)e << 12) | ((u32)n << 6) | (u32)m;
  }
  itot[0] = t;
}

// ---------------------------------------------------------------------------
// Pre-gather + convert: Xe[e][p][k] = bf16(x[ridx[e][p]][k]).
__global__ void gather_cvt(const float* __restrict__ x,
                           const int* __restrict__ cnt,
                           const u16* __restrict__ ridx,
                           u16* __restrict__ Xe) {
  const int e = blockIdx.y, p = blockIdx.x;
  int c = cnt[e]; c = c < HS_CAP ? c : HS_CAP;
  if (p >= c) return;
  const int row = ridx[e * BATCH + p];
  const float* s = x + (size_t)row * DIN;
  u16* d = Xe + ((size_t)e * HS_CAP + p) * DIN;
  const int t = threadIdx.x;  // 128 threads x 8 elems = 1024
  const f32x4 a = *(const f32x4*)(s + t * 8);
  const f32x4 b = *(const f32x4*)(s + t * 8 + 4);
  u16x8 o;
  o[0] = f2bf(a[0]); o[1] = f2bf(a[1]); o[2] = f2bf(a[2]); o[3] = f2bf(a[3]);
  o[4] = f2bf(b[0]); o[5] = f2bf(b[1]); o[6] = f2bf(b[2]); o[7] = f2bf(b[3]);
  *(u16x8*)(d + t * 8) = o;
}

// ---------------------------------------------------------------------------
// Transpose + convert, 64x64 tiles, vectorized.
__global__ void transpose_cvt(const float* __restrict__ src, u16* __restrict__ dst,
                              int C, int ldd, size_t src_slice,
                              size_t dst_hi, size_t dst_lo) {
  __shared__ float ts[64][65];
  const int z = blockIdx.z;
  const float* s = src + (size_t)z * src_slice;
  u16* d = dst + (size_t)(z >> 2) * dst_hi + (size_t)(z & 3) * dst_lo;
  const int c0 = blockIdx.x * 64, r0 = blockIdx.y * 64;
  const int t = threadIdx.x;
  const int lr = t >> 4, lc = (t & 15) * 4;
#pragma unroll
  for (int i = 0; i < 4; ++i) {
    const f32x4 v = *(const f32x4*)(s + (size_t)(r0 + i * 16 + lr) * C + c0 + lc);
    ts[i * 16 + lr][lc] = v[0];
    ts[i * 16 + lr][lc + 1] = v[1];
    ts[i * 16 + lr][lc + 2] = v[2];
    ts[i * 16 + lr][lc + 3] = v[3];
  }
  __syncthreads();
  const int cc = t >> 3, r8 = (t & 7) * 8;
#pragma unroll
  for (int pass = 0; pass < 2; ++pass) {
    const int c = cc + pass * 32;
    u16x8 o;
#pragma unroll
    for (int j = 0; j < 8; ++j) o[j] = f2bf(ts[r8 + j][c]);
    *(u16x8*)(d + (size_t)(c0 + c) * ldd + r0 + r8) = o;
  }
}

// ---------------------------------------------------------------------------
// Shared GEMM micro-kernels (round-9-verified core pieces).
__device__ __forceinline__ void rdB4(i32x4 rB[2][2], const char* base, int wc,
                                     int roff, int NH) {
#pragma unroll
  for (int n = 0; n < 2; ++n)
#pragma unroll
    for (int kk = 0; kk < 2; ++kk)
      rB[n][kk] = *(const i32x4*)(base + (((wc * 4 + NH * 2 + n) * 2 + kk) << 10) + roff);
}
template <int MH>
__device__ __forceinline__ void rdA8(i32x4 rA[4][2], const char* base, int wr, int roff) {
#pragma unroll
  for (int m = 0; m < 4; ++m)
#pragma unroll
    for (int kk = 0; kk < 2; ++kk)
      rA[m][kk] = *(const i32x4*)(base + (((wr * 8 + MH * 4 + m) * 2 + kk) << 10) + roff);
}
template <int MH, int NH>
__device__ __forceinline__ void mm16(f32x4 acc[8][4], const i32x4 rA[4][2],
                                     const i32x4 rB[2][2]) {
  __builtin_amdgcn_s_setprio(1);
#pragma unroll
  for (int m = 0; m < 4; ++m)
#pragma unroll
    for (int n = 0; n < 2; ++n)
#pragma unroll
      for (int kk = 0; kk < 2; ++kk)
        acc[MH * 4 + m][NH * 2 + n] = __builtin_amdgcn_mfma_f32_16x16x32_bf16(
            __builtin_bit_cast(bf16x8, rA[m][kk]),
            __builtin_bit_cast(bf16x8, rB[n][kk]),
            acc[MH * 4 + m][NH * 2 + n], 0, 0, 0);
  __builtin_amdgcn_s_setprio(0);
}

// K-loop over NT 64-wide tiles (both operands staged through swizzled LDS).
#define TILE_BODY(T, CA, CB_, DA_OT, DB_CB)                                    \
  {                                                                            \
    const int t_ = (T);                                                        \
    const bool g1 = (t_ + 1) < NT, g2 = (t_ + 2) < NT;                         \
    const int kA = (t_ + 1) * 64, kB = (t_ + 2) * 64;                          \
    rdA8<0>(rA, CA, wr, roff);                                                 \
    rdB4(rB0, CB_, wc, roff, 0);                                               \
    if (g1) STG4(qA0, qA1, kA, DA_OT);                                         \
    BAR();                                                                     \
    mm16<0, 0>(acc, rA, rB0);                                                  \
    BAR();                                                                     \
    rdB4(rB1, CB_, wc, roff, 1);                                               \
    if (g1) STG4(qA2, qA3, kA, DA_OT + 8192);                                  \
    BAR();                                                                     \
    mm16<0, 1>(acc, rA, rB1);                                                  \
    BAR();                                                                     \
    rdA8<1>(rA, CA, wr, roff);                                                 \
    if (g2) STG4(qB0, qB1, kB, DB_CB);                                         \
    BAR();                                                                     \
    mm16<1, 1>(acc, rA, rB1);                                                  \
    BAR();                                                                     \
    if (g2) {                                                                  \
      STG4(qB2, qB3, kB, DB_CB + 8192);                                        \
      BAR();                                                                   \
      mm16<1, 0>(acc, rA, rB0);                                                \
      VM4();                                                                   \
    } else {                                                                   \
      BAR();                                                                   \
      mm16<1, 0>(acc, rA, rB0);                                                \
      VM0();                                                                   \
    }                                                                          \
    BAR();                                                                     \
  }

// ---------------------------------------------------------------------------
// Persistent L1: 256 blocks (1/CU), each processes a contiguous item range of
// the device-built work list. Item = one 256x256 output tile of expert e.
__global__ __launch_bounds__(512, 2) void gemm256p(
    const u16* __restrict__ Xe, const u16* __restrict__ w1t,
    u16* __restrict__ Hs, const float* __restrict__ wgt,
    const float* __restrict__ b1,
    const int* __restrict__ cnt, const u16* __restrict__ ridx,
    const int* __restrict__ itot, const u32* __restrict__ items) {
  __shared__ __align__(16) u16 sA[2][16384];
  __shared__ __align__(16) u16 sB[2][16384];

  const int tid = threadIdx.x;
  const int w = tid >> 6, lane = tid & 63;
  const int l15 = lane & 15, lh = lane >> 4;
  const int wr = w >> 2, wc = w & 3;               // 2(M) x 4(N) waves

  const int lp = lane ^ ((lane & 32) >> 4);        // pre-swizzled source coords
  const int grow = (w >> 1) * 16 + (lp >> 2);
  const int gcol = (w & 1) * 32 + (lp & 3) * 8;
  const int roff = l15 * 64 + ((lh * 16) ^ ((l15 & 8) << 2));
  const char* cA0 = (const char*)&sA[0][0];
  const char* cA1 = (const char*)&sA[1][0];
  const char* cB0 = (const char*)&sB[0][0];
  const char* cB1 = (const char*)&sB[1][0];
  u16* dA0 = &sA[0][w * 512];
  u16* dA1 = &sA[1][w * 512];
  u16* dB0 = &sB[0][w * 512];
  u16* dB1 = &sB[1][w * 512];

  const int total = itot[0];
  const int lo = (int)(((long)blockIdx.x * total) >> 8);
  const int hi = (int)((((long)blockIdx.x + 1) * total) >> 8);
  constexpr int NT = DIN / 64;                     // 16

  for (int ii = lo; ii < hi; ++ii) {
    const u32 it = items[ii];
    const int e = it >> 12, n = (it >> 6) & 63, m = it & 63;
    const int bM = m * 256, bN = n * 256;
    int count = cnt[e]; count = count < HS_CAP ? count : HS_CAP;
    const int eoff = e * BATCH;

    const u16* A = Xe + (size_t)e * HS_CAP * DIN;
    const u16* Bt = w1t + (size_t)e * DH * DIN;
    const float* bias = b1 + (size_t)e * DH;
    u16* dstH = Hs + (size_t)e * HS_CAP * DH;

    const u16* qA0 = A + (size_t)(bM + grow) * DIN + gcol;
    const u16* qA1 = qA0 + (size_t)64 * DIN;
    const u16* qA2 = qA0 + (size_t)128 * DIN;
    const u16* qA3 = qA0 + (size_t)192 * DIN;
    const u16* qB0 = Bt + (size_t)(bN + grow) * DIN + gcol;
    const u16* qB1 = qB0 + (size_t)64 * DIN;
    const u16* qB2 = qB0 + (size_t)128 * DIN;
    const u16* qB3 = qB0 + (size_t)192 * DIN;

    f32x4 acc[8][4] = {};
    i32x4 rA[4][2], rB0[2][2], rB1[2][2];

    STG4(qB0, qB1, 0, dB0);
    STG4(qB2, qB3, 0, dB0 + 8192);
    STG4(qA0, qA1, 0, dA0);
    STG4(qA2, qA3, 0, dA0 + 8192);
    STG4(qB0, qB1, 64, dB1);
    STG4(qB2, qB3, 64, dB1 + 8192);
    VM4();
    BAR();

    for (int t = 0; t < NT; t += 2) {
      TILE_BODY(t, cA0, cB0, dA1, dB0);
      TILE_BODY(t + 1, cA1, cB1, dA0, dB1);
    }

    // epilogue (EPI=0). C/D: col = l15, row = lh*4 + r [m89-verified]
#pragma unroll
    for (int m2 = 0; m2 < 8; ++m2)
#pragma unroll
      for (int r = 0; r < 4; ++r) {
        const int pos = bM + wr * 128 + m2 * 16 + lh * 4 + r;
        if (pos >= count) continue;
        const int orow = ridx[eoff + pos];
        const float wsc = wgt[(size_t)orow * NEXP + e];
#pragma unroll
        for (int nn = 0; nn < 4; ++nn) {
          const int col = bN + wc * 64 + nn * 16 + l15;
          float v = acc[m2][nn][r] + bias[col];
          v = fmaxf(v, 0.0f) * wsc;
          dstH[(size_t)pos * DH + col] = f2bf(v);
        }
      }
  }
}

// ---------------------------------------------------------------------------
// Grid-launched GEMM (round-9 core) — used for L2 (EPI=2) and L1 fallback.
template <int EPI>
__global__ __launch_bounds__(512, 2) void gemm256(
    const u16* __restrict__ A0, int lda,
    const u16* __restrict__ Bt0, int ldb, int K,
    u16* __restrict__ dstH0, Ptr4 parts,
    const float* __restrict__ wgt, const float* __restrict__ bias0,
    const int* __restrict__ cnt, const u16* __restrict__ ridx, int camp,
    int NM, int NN) {
  __shared__ __align__(16) u16 sA[2][16384];
  __shared__ __align__(16) u16 sB[2][16384];

  const int tid = threadIdx.x;
  const int w = tid >> 6, lane = tid & 63;
  const int l15 = lane & 15, lh = lane >> 4;
  const int wr = w >> 2, wc = w & 3;               // 2(M) x 4(N) waves

  // bijective XCD chunking (gridDim.x % 8 == 0) + M-fastest decode
  const int cpx = (int)gridDim.x >> 3;
  const int id = blockIdx.x;
  const int wk = (id & 7) * cpx + (id >> 3);
  const int m = wk % NM;
  const int n = (wk / NM) % NN;
  const int z = wk / (NM * NN);
  const int bM = m * 256, bN = n * 256;

  const int expert = camp * 4 + z;
  int count = cnt[expert];
  count = count < HS_CAP ? count : HS_CAP;
  if (bM >= count) return;
  const int eoff = expert * BATCH;

  const u16* A;
  const u16* Bt;
  const float* bias = bias0;
  u16* dstH = dstH0;
  if (EPI == 0) {
    A = A0 + (size_t)expert * HS_CAP * lda;        // compacted Xe
    Bt = Bt0 + (size_t)expert * DH * DIN;
    bias = bias0 + (size_t)expert * DH;
    dstH = dstH0 + (size_t)z * HS_CAP * DH;
  } else {
    A = A0 + (size_t)z * HS_CAP * lda;             // Hs position space
    Bt = Bt0 + (size_t)z * DH;                     // expert-slot K-window
  }

  const int lp = lane ^ ((lane & 32) >> 4);
  const int grow = (w >> 1) * 16 + (lp >> 2);
  const int gcol = (w & 1) * 32 + (lp & 3) * 8;

  const u16* qA0 = A + (size_t)(bM + grow) * lda + gcol;
  const u16* qA1 = qA0 + (size_t)64 * lda;
  const u16* qA2 = qA0 + (size_t)128 * lda;
  const u16* qA3 = qA0 + (size_t)192 * lda;
  const u16* qB0 = Bt + (size_t)(bN + grow) * ldb + gcol;
  const u16* qB1 = qB0 + (size_t)64 * ldb;
  const u16* qB2 = qB0 + (size_t)128 * ldb;
  const u16* qB3 = qB0 + (size_t)192 * ldb;

  u16* dA0 = &sA[0][w * 512];
  u16* dA1 = &sA[1][w * 512];
  u16* dB0 = &sB[0][w * 512];
  u16* dB1 = &sB[1][w * 512];

  const int roff = l15 * 64 + ((lh * 16) ^ ((l15 & 8) << 2));
  const char* cA0 = (const char*)&sA[0][0];
  const char* cA1 = (const char*)&sA[1][0];
  const char* cB0 = (const char*)&sB[0][0];
  const char* cB1 = (const char*)&sB[1][0];

  const int NT = K >> 6;
  f32x4 acc[8][4] = {};
  i32x4 rA[4][2], rB0[2][2], rB1[2][2];

  STG4(qB0, qB1, 0, dB0);
  STG4(qB2, qB3, 0, dB0 + 8192);
  STG4(qA0, qA1, 0, dA0);
  STG4(qA2, qA3, 0, dA0 + 8192);
  STG4(qB0, qB1, 64, dB1);
  STG4(qB2, qB3, 64, dB1 + 8192);
  VM4();
  BAR();

  for (int t = 0; t < NT; t += 2) {
    TILE_BODY(t, cA0, cB0, dA1, dB0);
    TILE_BODY(t + 1, cA1, cB1, dA0, dB1);
  }

  if (EPI == 0) {
#pragma unroll
    for (int m2 = 0; m2 < 8; ++m2)
#pragma unroll
      for (int r = 0; r < 4; ++r) {
        const int pos = bM + wr * 128 + m2 * 16 + lh * 4 + r;
        if (pos >= count) continue;
        const int orow = ridx[eoff + pos];
        const float wsc = wgt[(size_t)orow * NEXP + expert];
#pragma unroll
        for (int nn = 0; nn < 4; ++nn) {
          const int col = bN + wc * 64 + nn * 16 + l15;
          float v = acc[m2][nn][r] + bias[col];
          v = fmaxf(v, 0.0f) * wsc;
          dstH[(size_t)pos * DH + col] = f2bf(v);
        }
      }
  } else {
    float* __restrict__ P = parts.p[z];
#pragma unroll
    for (int m2 = 0; m2 < 8; ++m2)
#pragma unroll
      for (int r = 0; r < 4; ++r) {
        const int pos = bM + wr * 128 + m2 * 16 + lh * 4 + r;
        if (pos >= count) continue;
        const int orow = ridx[eoff + pos];
#pragma unroll
        for (int nn = 0; nn < 4; ++nn) {
          const int col = bN + wc * 64 + nn * 16 + l15;
          P[(size_t)orow * DOUT + col] = acc[m2][nn][r];
        }
      }
  }
}

// ---------------------------------------------------------------------------
// Reduce masked partials + weight-folded b2 bias (SELECT, never multiply).
__global__ void reduce_kernel(float* __restrict__ dst,
                              const float* __restrict__ p0, const float* __restrict__ p1,
                              const float* __restrict__ p2, const float* __restrict__ p3,
                              const float* __restrict__ wgt,
                              const float* __restrict__ b2c, int camp) {
  const int b = blockIdx.x, t = threadIdx.x;
  const f32x4 wv = *(const f32x4*)(wgt + (size_t)b * NEXP + camp * 4);
  const size_t ro = (size_t)b * DOUT;
#pragma unroll
  for (int j = 0; j < 4; ++j) {
    const int i = j * 256 + t;
    float acc = wv[0] * b2c[i] + wv[1] * b2c[DOUT + i] +
                wv[2] * b2c[2 * DOUT + i] + wv[3] * b2c[3 * DOUT + i];
    acc += (wv[0] != 0.f) ? p0[ro + i] : 0.f;
    acc += (wv[1] != 0.f) ? p1[ro + i] : 0.f;
    acc += (wv[2] != 0.f) ? p2[ro + i] : 0.f;
    acc += (wv[3] != 0.f) ? p3[ro + i] : 0.f;
    dst[ro + i] = acc;
  }
}

// ---------------------------------------------------------------------------
__global__ void final_kernel(float* __restrict__ out,
                             const float* __restrict__ alpha,
                             const float* __restrict__ beta) {
  const int b = blockIdx.x, t = threadIdx.x;
  const float* pa = out + (size_t)BATCH * DOUT + (size_t)b * DOUT;
  const float* pg = out + (size_t)2 * BATCH * DOUT + (size_t)b * DOUT;
  float* po = out + (size_t)b * DOUT;
  float d[4], s1 = 0.f, s2 = 0.f;
#pragma unroll
  for (int j = 0; j < 4; ++j) {
    const int i = j * 256 + t;
    d[j] = pa[i] - pg[i];
    s1 += d[j];
    s2 += d[j] * d[j];
  }
#pragma unroll
  for (int off = 32; off; off >>= 1) {
    s1 += __shfl_xor(s1, off);
    s2 += __shfl_xor(s2, off);
  }
  __shared__ float r1[4], r2[4];
  if ((t & 63) == 0) { r1[t >> 6] = s1; r2[t >> 6] = s2; }
  __syncthreads();
  s1 = r1[0] + r1[1] + r1[2] + r1[3];
  s2 = r2[0] + r2[1] + r2[2] + r2[3];
  const float mean = s1 * (1.f / DOUT);
  const float var = s2 * (1.f / DOUT) - mean * mean;  // population var
  const float dist = sqrtf(s2) * (1.f + var);
  const float zz = alpha[0] * dist + beta[0];
  const float corr = 2.f / (1.f + expf(-zz));
#pragma unroll
  for (int j = 0; j < 4; ++j) po[j * 256 + t] = d[j] * corr;
}

// ---------------------------------------------------------------------------
extern "C" void kernel_launch(void* const* d_in, const int* in_sizes, int n_in,
                              void* d_out, int out_size, void* d_ws, size_t ws_size,
                              hipStream_t stream) {
  const float* x   = (const float*)d_in[0];
  const float* gw  = (const float*)d_in[1];
  const float* gb  = (const float*)d_in[2];
  const float* w1  = (const float*)d_in[3];
  const float* b1  = (const float*)d_in[4];
  const float* w2  = (const float*)d_in[5];
  const float* b2  = (const float*)d_in[6];
  const float* pha = (const float*)d_in[7];
  const float* phb = (const float*)d_in[8];
  float* out = (float*)d_out;  // [output | out_a | out_g], each BATCH*DOUT f32
  float* out_a = out + (size_t)BATCH * DOUT;
  float* out_g = out + (size_t)2 * BATCH * DOUT;

  char* ws = (char*)d_ws;
  float* wgt  = (float*)ws;
  int* cnt    = (int*)(ws + 131072);
  u16* ridx   = (u16*)(ws + 135168);
  u32* items  = (u32*)(ws + 200704);   // <= 1408*4 B
  int* itot   = (int*)(ws + 258048);
  u16* Xe     = (u16*)(ws + 262144);
  constexpr size_t XE_BYTES  = (size_t)NEXP * HS_CAP * DIN * 2;   // 46.1 MB
  constexpr size_t W1T_BYTES = (size_t)NEXP * DH * DIN * 2;       // 64 MB
  constexpr size_t W2T_BYTES = (size_t)DOUT * 4 * DH * 2;         // 32 MB/camp
  constexpr size_t P_BYTES   = (size_t)BATCH * DOUT * 4;          // 16 MB
  constexpr size_t HS_E      = (size_t)HS_CAP * DH * 2;           // 23 MB/expert
  const size_t w1t_off = 262144 + XE_BYTES;
  u16* w1t = (u16*)(ws + w1t_off);

  const size_t merged_need = w1t_off + W1T_BYTES + 2 * P_BYTES + 8 * HS_E;
  const bool merged = (ws_size >= merged_need);

  constexpr int NM = HS_CAP / 256;                 // 11
  constexpr int NN1 = DH / 256, NN2 = DOUT / 256;  // 16, 4

  // common prep
  gate_kernel<<<BATCH / 4, 256, 0, stream>>>(x, gw, gb, wgt);
  hipMemsetAsync(cnt, 0, NEXP * sizeof(int), stream);
  assign_kernel<<<BATCH / 256, 256, 0, stream>>>(wgt, cnt, ridx);
  build_items<<<1, 64, 0, stream>>>(cnt, items, itot);
  gather_cvt<<<dim3(HS_CAP, NEXP), 128, 0, stream>>>(x, cnt, ridx, Xe);
  transpose_cvt<<<dim3(DH / 64, DIN / 64, NEXP), 256, 0, stream>>>(
      w1, w1t, DH, DIN, (size_t)DIN * DH, (size_t)4 * DH * DIN, (size_t)DH * DIN);

  if (merged) {
    float* P0 = (float*)(ws + w1t_off + W1T_BYTES);
    float* P1 = (float*)(ws + w1t_off + W1T_BYTES + P_BYTES);
    u16* Hs   = (u16*)(ws + w1t_off + W1T_BYTES + 2 * P_BYTES);
    u16* w2t0 = w1t;                               // recycled after merged L1
    u16* w2t1 = (u16*)((char*)w1t + W2T_BYTES);
    Ptr4 pc0 = {{out_a, out, out_g, P0}};
    Ptr4 pc1 = {{out_g, out, P0, P1}};

    // merged persistent L1: 256 blocks (1/CU), device work-list
    gemm256p<<<256, 512, 0, stream>>>(Xe, w1t, Hs, wgt, b1, cnt, ridx, itot, items);
    // w1t dead now -> both w2 transposes into it
    transpose_cvt<<<dim3(DOUT / 64, DH / 64, 4), 256, 0, stream>>>(
        w2, w2t0, DOUT, 4 * DH, (size_t)DH * DOUT, 0, (size_t)DH);
    transpose_cvt<<<dim3(DOUT / 64, DH / 64, 4), 256, 0, stream>>>(
        w2 + (size_t)4 * DH * DOUT, w2t1, DOUT, 4 * DH, (size_t)DH * DOUT, 0, (size_t)DH);

    gemm256<2><<<NM * NN2 * 4, 512, 0, stream>>>(
        Hs, DH, w2t0, 4 * DH, DH, nullptr, pc0, nullptr, nullptr, cnt, ridx, 0, NM, NN2);
    reduce_kernel<<<BATCH, 256, 0, stream>>>(out_a, out_a, out, out_g, P0, wgt, b2, 0);
    gemm256<2><<<NM * NN2 * 4, 512, 0, stream>>>(
        Hs + (size_t)4 * HS_CAP * DH, DH, w2t1, 4 * DH, DH, nullptr, pc1,
        nullptr, nullptr, cnt, ridx, 1, NM, NN2);
    reduce_kernel<<<BATCH, 256, 0, stream>>>(out_g, out_g, out, P0, P1, wgt,
                                             b2 + (size_t)4 * DOUT, 1);
  } else {
    // sequential fallback (round-9 structure)
    u16* w2t1 = w1t;                               // recycled after camp0 L1
    u16* w2t0 = (u16*)(ws + w1t_off + W1T_BYTES);
    float* P0 = (float*)(ws + w1t_off + W1T_BYTES + W2T_BYTES);
    float* P1 = (float*)(ws + w1t_off + W1T_BYTES + W2T_BYTES + P_BYTES);
    u16* Hs   = (u16*)(ws + w1t_off + W1T_BYTES + W2T_BYTES + 2 * P_BYTES);
    Ptr4 pc0 = {{out_a, out, out_g, P0}};
    Ptr4 pc1 = {{out_g, out, P0, P1}};

    transpose_cvt<<<dim3(DOUT / 64, DH / 64, 4), 256, 0, stream>>>(
        w2, w2t0, DOUT, 4 * DH, (size_t)DH * DOUT, 0, (size_t)DH);
    gemm256<0><<<NM * NN1 * 4, 512, 0, stream>>>(
        Xe, DIN, w1t, DIN, DIN, Hs, pc0, wgt, b1, cnt, ridx, 0, NM, NN1);
    transpose_cvt<<<dim3(DOUT / 64, DH / 64, 4), 256, 0, stream>>>(
        w2 + (size_t)4 * DH * DOUT, w2t1, DOUT, 4 * DH, (size_t)DH * DOUT, 0, (size_t)DH);
    gemm256<2><<<NM * NN2 * 4, 512, 0, stream>>>(
        Hs, DH, w2t0, 4 * DH, DH, nullptr, pc0, nullptr, nullptr, cnt, ridx, 0, NM, NN2);
    reduce_kernel<<<BATCH, 256, 0, stream>>>(out_a, out_a, out, out_g, P0, wgt, b2, 0);
    gemm256<0><<<NM * NN1 * 4, 512, 0, stream>>>(
        Xe, DIN, w1t, DIN, DIN, Hs, pc1, wgt, b1, cnt, ridx, 1, NM, NN1);
    gemm256<2><<<NM * NN2 * 4, 512, 0, stream>>>(
        Hs, DH, w2t1, 4 * DH, DH, nullptr, pc1, nullptr, nullptr, cnt, ridx, 1, NM, NN2);
    reduce_kernel<<<BATCH, 256, 0, stream>>>(out_g, out_g, out, P0, P1, wgt,
                                             b2 + (size_t)4 * DOUT, 1);
  }

  final_kernel<<<BATCH, 256, 0, stream>>>(out, pha, phb);
}

// Round 13
// 650.834 us; speedup vs baseline: 1.1190x; 1.1190x over previous
//
#include <hip/hip_runtime.h>
#include <hip/hip_bf16.h>
#include <stdint.h>

typedef unsigned short u16;
typedef unsigned int u32;
typedef __attribute__((ext_vector_type(4))) float f32x4;
typedef __attribute__((ext_vector_type(4))) int i32x4;
typedef __attribute__((ext_vector_type(8))) u16 u16x8;
typedef __attribute__((ext_vector_type(8))) __bf16 bf16x8;

constexpr int BATCH = 4096, DIN = 1024, DH = 4096, DOUT = 1024, NEXP = 8;
constexpr int HS_CAP = 2816;  // per-expert row capacity (mean 2560, +8.2 sigma)

struct Ptr4 { float* p[4]; };

__device__ __forceinline__ u16 f2bf(float f) {
  u32 u = __float_as_uint(f);
  u += 0x7fffu + ((u >> 16) & 1u);   // RNE (finite values only here)
  return (u16)(u >> 16);
}

// global -> LDS direct copy, 16B per lane. LDS dest is wave-uniform base;
// HW adds lane*16.
#define GLOAD_LDS16(gp, lp)                                                    \
  __builtin_amdgcn_global_load_lds(                                           \
      (__attribute__((address_space(1))) void*)(gp),                          \
      (__attribute__((address_space(3))) void*)(lp), 16, 0, 0)

#define BAR()                                                                  \
  { asm volatile("" ::: "memory"); __builtin_amdgcn_s_barrier();               \
    asm volatile("" ::: "memory"); }
#define VM4() asm volatile("s_waitcnt vmcnt(4)" ::: "memory")
#define VM0() asm volatile("s_waitcnt vmcnt(0)" ::: "memory")

// stage 128 rows (two 64-row groups via row-base pointers q0,q1)
#define STG4(q0, q1, kofs, dst)                                                \
  { GLOAD_LDS16((q0) + (kofs), (dst));                                         \
    GLOAD_LDS16((q1) + (kofs), (dst) + 4096); }

// ---------------------------------------------------------------------------
// Gate: scores = (x @ gate_w + gate_b)/e, softmax, top-5 mask, renorm.
__global__ void gate_kernel(const float* __restrict__ x,
                            const float* __restrict__ gw,
                            const float* __restrict__ gb,
                            float* __restrict__ wgt) {
  const int wave = threadIdx.x >> 6, lane = threadIdx.x & 63;
  const int b = blockIdx.x * 4 + wave;
  const float* xr = x + (size_t)b * DIN;
  float acc[NEXP];
#pragma unroll
  for (int e = 0; e < NEXP; ++e) acc[e] = 0.f;
  for (int k = lane; k < DIN; k += 64) {
    const float xv = xr[k];
    const f32x4 g0 = *(const f32x4*)(gw + (size_t)k * NEXP);
    const f32x4 g1 = *(const f32x4*)(gw + (size_t)k * NEXP + 4);
    acc[0] += xv * g0[0]; acc[1] += xv * g0[1];
    acc[2] += xv * g0[2]; acc[3] += xv * g0[3];
    acc[4] += xv * g1[0]; acc[5] += xv * g1[1];
    acc[6] += xv * g1[2]; acc[7] += xv * g1[3];
  }
#pragma unroll
  for (int off = 32; off; off >>= 1)
#pragma unroll
    for (int e = 0; e < NEXP; ++e) acc[e] += __shfl_xor(acc[e], off);
  if (lane == 0) {
    const float invT = 0.36787944117144233f;  // 1/e
    float s[NEXP], mx = -1e30f;
    for (int e = 0; e < NEXP; ++e) { s[e] = (acc[e] + gb[e]) * invT; mx = fmaxf(mx, s[e]); }
    float p[NEXP], sum = 0.f;
    for (int e = 0; e < NEXP; ++e) { p[e] = expf(s[e] - mx); sum += p[e]; }
    const float inv = 1.f / sum;
    for (int e = 0; e < NEXP; ++e) p[e] *= inv;
    float w[NEXP], wsum = 0.f;
    for (int e = 0; e < NEXP; ++e) {
      int cnt = 0;
      for (int j = 0; j < NEXP; ++j) cnt += (p[j] > p[e]) || (p[j] == p[e] && j < e);
      w[e] = (cnt < 5) ? p[e] : 0.f;   // top-5 of 8
      wsum += w[e];
    }
    const float inv2 = 1.f / (wsum + 1e-8f);
    for (int e = 0; e < NEXP; ++e) wgt[(size_t)b * NEXP + e] = w[e] * inv2;
  }
}

// ---------------------------------------------------------------------------
// Per-expert row compaction (order-independent output).
__global__ void assign_kernel(const float* __restrict__ wgt,
                              int* __restrict__ cnt, u16* __restrict__ ridx) {
  const int b = blockIdx.x * 256 + threadIdx.x;
#pragma unroll
  for (int e = 0; e < NEXP; ++e) {
    if (wgt[(size_t)b * NEXP + e] != 0.f) {
      const int pos = atomicAdd(&cnt[e], 1);
      if (pos < BATCH) ridx[e * BATCH + pos] = (u16)b;
    }
  }
}

// ---------------------------------------------------------------------------
// Pre-gather + convert: Xe[e][p][k] = bf16(x[ridx[e][p]][k]).
__global__ void gather_cvt(const float* __restrict__ x,
                           const int* __restrict__ cnt,
                           const u16* __restrict__ ridx,
                           u16* __restrict__ Xe) {
  const int e = blockIdx.y, p = blockIdx.x;
  int c = cnt[e]; c = c < HS_CAP ? c : HS_CAP;
  if (p >= c) return;
  const int row = ridx[e * BATCH + p];
  const float* s = x + (size_t)row * DIN;
  u16* d = Xe + ((size_t)e * HS_CAP + p) * DIN;
  const int t = threadIdx.x;  // 128 threads x 8 elems = 1024
  const f32x4 a = *(const f32x4*)(s + t * 8);
  const f32x4 b = *(const f32x4*)(s + t * 8 + 4);
  u16x8 o;
  o[0] = f2bf(a[0]); o[1] = f2bf(a[1]); o[2] = f2bf(a[2]); o[3] = f2bf(a[3]);
  o[4] = f2bf(b[0]); o[5] = f2bf(b[1]); o[6] = f2bf(b[2]); o[7] = f2bf(b[3]);
  *(u16x8*)(d + t * 8) = o;
}

// ---------------------------------------------------------------------------
// Transpose + convert, 64x64 tiles, vectorized.
__global__ void transpose_cvt(const float* __restrict__ src, u16* __restrict__ dst,
                              int C, int ldd, size_t src_slice,
                              size_t dst_hi, size_t dst_lo) {
  __shared__ float ts[64][65];
  const int z = blockIdx.z;
  const float* s = src + (size_t)z * src_slice;
  u16* d = dst + (size_t)(z >> 2) * dst_hi + (size_t)(z & 3) * dst_lo;
  const int c0 = blockIdx.x * 64, r0 = blockIdx.y * 64;
  const int t = threadIdx.x;
  const int lr = t >> 4, lc = (t & 15) * 4;
#pragma unroll
  for (int i = 0; i < 4; ++i) {
    const f32x4 v = *(const f32x4*)(s + (size_t)(r0 + i * 16 + lr) * C + c0 + lc);
    ts[i * 16 + lr][lc] = v[0];
    ts[i * 16 + lr][lc + 1] = v[1];
    ts[i * 16 + lr][lc + 2] = v[2];
    ts[i * 16 + lr][lc + 3] = v[3];
  }
  __syncthreads();
  const int cc = t >> 3, r8 = (t & 7) * 8;
#pragma unroll
  for (int pass = 0; pass < 2; ++pass) {
    const int c = cc + pass * 32;
    u16x8 o;
#pragma unroll
    for (int j = 0; j < 8; ++j) o[j] = f2bf(ts[r8 + j][c]);
    *(u16x8*)(d + (size_t)(c0 + c) * ldd + r0 + r8) = o;
  }
}

// ---------------------------------------------------------------------------
// Shared GEMM micro-kernels (round-9-verified core pieces).
__device__ __forceinline__ void rdB4(i32x4 rB[2][2], const char* base, int wc,
                                     int roff, int NH) {
#pragma unroll
  for (int n = 0; n < 2; ++n)
#pragma unroll
    for (int kk = 0; kk < 2; ++kk)
      rB[n][kk] = *(const i32x4*)(base + (((wc * 4 + NH * 2 + n) * 2 + kk) << 10) + roff);
}
template <int MH>
__device__ __forceinline__ void rdA8(i32x4 rA[4][2], const char* base, int wr, int roff) {
#pragma unroll
  for (int m = 0; m < 4; ++m)
#pragma unroll
    for (int kk = 0; kk < 2; ++kk)
      rA[m][kk] = *(const i32x4*)(base + (((wr * 8 + MH * 4 + m) * 2 + kk) << 10) + roff);
}
template <int MH, int NH>
__device__ __forceinline__ void mm16(f32x4 acc[8][4], const i32x4 rA[4][2],
                                     const i32x4 rB[2][2]) {
  __builtin_amdgcn_s_setprio(1);
#pragma unroll
  for (int m = 0; m < 4; ++m)
#pragma unroll
    for (int n = 0; n < 2; ++n)
#pragma unroll
      for (int kk = 0; kk < 2; ++kk)
        acc[MH * 4 + m][NH * 2 + n] = __builtin_amdgcn_mfma_f32_16x16x32_bf16(
            __builtin_bit_cast(bf16x8, rA[m][kk]),
            __builtin_bit_cast(bf16x8, rB[n][kk]),
            acc[MH * 4 + m][NH * 2 + n], 0, 0, 0);
  __builtin_amdgcn_s_setprio(0);
}

// K-loop over NT 64-wide tiles (both operands staged through swizzled LDS).
#define TILE_BODY(T, CA, CB_, DA_OT, DB_CB)                                    \
  {                                                                            \
    const int t_ = (T);                                                        \
    const bool g1 = (t_ + 1) < NT, g2 = (t_ + 2) < NT;                         \
    const int kA = (t_ + 1) * 64, kB = (t_ + 2) * 64;                          \
    rdA8<0>(rA, CA, wr, roff);                                                 \
    rdB4(rB0, CB_, wc, roff, 0);                                               \
    if (g1) STG4(qA0, qA1, kA, DA_OT);                                         \
    BAR();                                                                     \
    mm16<0, 0>(acc, rA, rB0);                                                  \
    BAR();                                                                     \
    rdB4(rB1, CB_, wc, roff, 1);                                               \
    if (g1) STG4(qA2, qA3, kA, DA_OT + 8192);                                  \
    BAR();                                                                     \
    mm16<0, 1>(acc, rA, rB1);                                                  \
    BAR();                                                                     \
    rdA8<1>(rA, CA, wr, roff);                                                 \
    if (g2) STG4(qB0, qB1, kB, DB_CB);                                         \
    BAR();                                                                     \
    mm16<1, 1>(acc, rA, rB1);                                                  \
    BAR();                                                                     \
    if (g2) {                                                                  \
      STG4(qB2, qB3, kB, DB_CB + 8192);                                        \
      BAR();                                                                   \
      mm16<1, 0>(acc, rA, rB0);                                                \
      VM4();                                                                   \
    } else {                                                                   \
      BAR();                                                                   \
      mm16<1, 0>(acc, rA, rB0);                                                \
      VM0();                                                                   \
    }                                                                          \
    BAR();                                                                     \
  }

// ---------------------------------------------------------------------------
// Grid-launched GEMM (round-9 core) — L1 (EPI=0) and L2 (EPI=2).
template <int EPI>
__global__ __launch_bounds__(512, 2) void gemm256(
    const u16* __restrict__ A0, int lda,
    const u16* __restrict__ Bt0, int ldb, int K,
    u16* __restrict__ dstH0, Ptr4 parts,
    const float* __restrict__ wgt, const float* __restrict__ bias0,
    const int* __restrict__ cnt, const u16* __restrict__ ridx, int camp,
    int NM, int NN) {
  __shared__ __align__(16) u16 sA[2][16384];
  __shared__ __align__(16) u16 sB[2][16384];

  const int tid = threadIdx.x;
  const int w = tid >> 6, lane = tid & 63;
  const int l15 = lane & 15, lh = lane >> 4;
  const int wr = w >> 2, wc = w & 3;               // 2(M) x 4(N) waves

  // bijective XCD chunking (gridDim.x % 8 == 0) + M-fastest decode
  const int cpx = (int)gridDim.x >> 3;
  const int id = blockIdx.x;
  const int wk = (id & 7) * cpx + (id >> 3);
  const int m = wk % NM;
  const int n = (wk / NM) % NN;
  const int z = wk / (NM * NN);
  const int bM = m * 256, bN = n * 256;

  const int expert = camp * 4 + z;
  int count = cnt[expert];
  count = count < HS_CAP ? count : HS_CAP;
  if (bM >= count) return;
  const int eoff = expert * BATCH;

  const u16* A;
  const u16* Bt;
  const float* bias = bias0;
  u16* dstH = dstH0;
  if (EPI == 0) {
    A = A0 + (size_t)expert * HS_CAP * lda;        // compacted Xe
    Bt = Bt0 + (size_t)expert * DH * DIN;
    bias = bias0 + (size_t)expert * DH;
    dstH = dstH0 + (size_t)z * HS_CAP * DH;
  } else {
    A = A0 + (size_t)z * HS_CAP * lda;             // Hs position space
    Bt = Bt0 + (size_t)z * DH;                     // expert-slot K-window
  }

  const int lp = lane ^ ((lane & 32) >> 4);
  const int grow = (w >> 1) * 16 + (lp >> 2);
  const int gcol = (w & 1) * 32 + (lp & 3) * 8;

  const u16* qA0 = A + (size_t)(bM + grow) * lda + gcol;
  const u16* qA1 = qA0 + (size_t)64 * lda;
  const u16* qA2 = qA0 + (size_t)128 * lda;
  const u16* qA3 = qA0 + (size_t)192 * lda;
  const u16* qB0 = Bt + (size_t)(bN + grow) * ldb + gcol;
  const u16* qB1 = qB0 + (size_t)64 * ldb;
  const u16* qB2 = qB0 + (size_t)128 * ldb;
  const u16* qB3 = qB0 + (size_t)192 * ldb;

  u16* dA0 = &sA[0][w * 512];
  u16* dA1 = &sA[1][w * 512];
  u16* dB0 = &sB[0][w * 512];
  u16* dB1 = &sB[1][w * 512];

  const int roff = l15 * 64 + ((lh * 16) ^ ((l15 & 8) << 2));
  const char* cA0 = (const char*)&sA[0][0];
  const char* cA1 = (const char*)&sA[1][0];
  const char* cB0 = (const char*)&sB[0][0];
  const char* cB1 = (const char*)&sB[1][0];

  const int NT = K >> 6;
  f32x4 acc[8][4] = {};
  i32x4 rA[4][2], rB0[2][2], rB1[2][2];

  STG4(qB0, qB1, 0, dB0);
  STG4(qB2, qB3, 0, dB0 + 8192);
  STG4(qA0, qA1, 0, dA0);
  STG4(qA2, qA3, 0, dA0 + 8192);
  STG4(qB0, qB1, 64, dB1);
  STG4(qB2, qB3, 64, dB1 + 8192);
  VM4();
  BAR();

  for (int t = 0; t < NT; t += 2) {
    TILE_BODY(t, cA0, cB0, dA1, dB0);
    TILE_BODY(t + 1, cA1, cB1, dA0, dB1);
  }

  if (EPI == 0) {
#pragma unroll
    for (int m2 = 0; m2 < 8; ++m2)
#pragma unroll
      for (int r = 0; r < 4; ++r) {
        const int pos = bM + wr * 128 + m2 * 16 + lh * 4 + r;
        if (pos >= count) continue;
        const int orow = ridx[eoff + pos];
        const float wsc = wgt[(size_t)orow * NEXP + expert];
#pragma unroll
        for (int nn = 0; nn < 4; ++nn) {
          const int col = bN + wc * 64 + nn * 16 + l15;
          float v = acc[m2][nn][r] + bias[col];
          v = fmaxf(v, 0.0f) * wsc;
          dstH[(size_t)pos * DH + col] = f2bf(v);
        }
      }
  } else {
    float* __restrict__ P = parts.p[z];
#pragma unroll
    for (int m2 = 0; m2 < 8; ++m2)
#pragma unroll
      for (int r = 0; r < 4; ++r) {
        const int pos = bM + wr * 128 + m2 * 16 + lh * 4 + r;
        if (pos >= count) continue;
        const int orow = ridx[eoff + pos];
#pragma unroll
        for (int nn = 0; nn < 4; ++nn) {
          const int col = bN + wc * 64 + nn * 16 + l15;
          P[(size_t)orow * DOUT + col] = acc[m2][nn][r];
        }
      }
  }
}

// ---------------------------------------------------------------------------
// Combined dispatch: blocks [0, l2n) run L2-camp0 (long blocks, dispatched
// first); blocks [l2n, grid) run L1-camp1 (short blocks backfill idle CUs).
// Data-disjoint: L2 reads Hs[0..3]/w2t0, writes pc0 partials; L1 reads
// Xe[4..7]/w1t, writes Hs[4..7].
__global__ __launch_bounds__(512, 2) void gemm_combo(
    const u16* __restrict__ Hs0, const u16* __restrict__ w2t0, Ptr4 pc0,
    const u16* __restrict__ Xe, const u16* __restrict__ w1t,
    u16* __restrict__ HsW, const float* __restrict__ b1,
    const float* __restrict__ wgt,
    const int* __restrict__ cnt, const u16* __restrict__ ridx, int l2n) {
  __shared__ __align__(16) u16 sA[2][16384];
  __shared__ __align__(16) u16 sB[2][16384];

  const int tid = threadIdx.x;
  const int w = tid >> 6, lane = tid & 63;
  const int l15 = lane & 15, lh = lane >> 4;
  const int wr = w >> 2, wc = w & 3;

  const bool isL2 = (int)blockIdx.x < l2n;
  const int id = isL2 ? (int)blockIdx.x : (int)blockIdx.x - l2n;
  const int tot = isL2 ? l2n : ((int)gridDim.x - l2n);   // 176 / 704, both %8==0
  const int cpx = tot >> 3;
  const int wk = (id & 7) * cpx + (id >> 3);
  const int NM = HS_CAP / 256;                           // 11
  const int NN = isL2 ? (DOUT / 256) : (DH / 256);       // 4 / 16
  const int m = wk % NM;
  const int n = (wk / NM) % NN;
  const int z = wk / (NM * NN);
  const int bM = m * 256, bN = n * 256;

  const int expert = isL2 ? z : 4 + z;
  int count = cnt[expert];
  count = count < HS_CAP ? count : HS_CAP;
  if (bM >= count) return;
  const int eoff = expert * BATCH;

  const u16* A; const u16* Bt;
  int lda, ldb, K;
  const float* bias = nullptr;
  u16* dstH = nullptr;
  if (isL2) {
    A = Hs0 + (size_t)z * HS_CAP * DH;  lda = DH;
    Bt = w2t0 + (size_t)z * DH;         ldb = 4 * DH;
    K = DH;
  } else {
    A = Xe + (size_t)expert * HS_CAP * DIN;  lda = DIN;
    Bt = w1t + (size_t)expert * DH * DIN;    ldb = DIN;
    K = DIN;
    bias = b1 + (size_t)expert * DH;
    dstH = HsW + (size_t)expert * HS_CAP * DH;
  }

  const int lp = lane ^ ((lane & 32) >> 4);
  const int grow = (w >> 1) * 16 + (lp >> 2);
  const int gcol = (w & 1) * 32 + (lp & 3) * 8;

  const u16* qA0 = A + (size_t)(bM + grow) * lda + gcol;
  const u16* qA1 = qA0 + (size_t)64 * lda;
  const u16* qA2 = qA0 + (size_t)128 * lda;
  const u16* qA3 = qA0 + (size_t)192 * lda;
  const u16* qB0 = Bt + (size_t)(bN + grow) * ldb + gcol;
  const u16* qB1 = qB0 + (size_t)64 * ldb;
  const u16* qB2 = qB0 + (size_t)128 * ldb;
  const u16* qB3 = qB0 + (size_t)192 * ldb;

  u16* dA0 = &sA[0][w * 512];
  u16* dA1 = &sA[1][w * 512];
  u16* dB0 = &sB[0][w * 512];
  u16* dB1 = &sB[1][w * 512];

  const int roff = l15 * 64 + ((lh * 16) ^ ((l15 & 8) << 2));
  const char* cA0 = (const char*)&sA[0][0];
  const char* cA1 = (const char*)&sA[1][0];
  const char* cB0 = (const char*)&sB[0][0];
  const char* cB1 = (const char*)&sB[1][0];

  const int NT = K >> 6;
  f32x4 acc[8][4] = {};
  i32x4 rA[4][2], rB0[2][2], rB1[2][2];

  STG4(qB0, qB1, 0, dB0);
  STG4(qB2, qB3, 0, dB0 + 8192);
  STG4(qA0, qA1, 0, dA0);
  STG4(qA2, qA3, 0, dA0 + 8192);
  STG4(qB0, qB1, 64, dB1);
  STG4(qB2, qB3, 64, dB1 + 8192);
  VM4();
  BAR();

  for (int t = 0; t < NT; t += 2) {
    TILE_BODY(t, cA0, cB0, dA1, dB0);
    TILE_BODY(t + 1, cA1, cB1, dA0, dB1);
  }

  if (isL2) {
    float* __restrict__ P = pc0.p[z];
#pragma unroll
    for (int m2 = 0; m2 < 8; ++m2)
#pragma unroll
      for (int r = 0; r < 4; ++r) {
        const int pos = bM + wr * 128 + m2 * 16 + lh * 4 + r;
        if (pos >= count) continue;
        const int orow = ridx[eoff + pos];
#pragma unroll
        for (int nn = 0; nn < 4; ++nn) {
          const int col = bN + wc * 64 + nn * 16 + l15;
          P[(size_t)orow * DOUT + col] = acc[m2][nn][r];
        }
      }
  } else {
#pragma unroll
    for (int m2 = 0; m2 < 8; ++m2)
#pragma unroll
      for (int r = 0; r < 4; ++r) {
        const int pos = bM + wr * 128 + m2 * 16 + lh * 4 + r;
        if (pos >= count) continue;
        const int orow = ridx[eoff + pos];
        const float wsc = wgt[(size_t)orow * NEXP + expert];
#pragma unroll
        for (int nn = 0; nn < 4; ++nn) {
          const int col = bN + wc * 64 + nn * 16 + l15;
          float v = acc[m2][nn][r] + bias[col];
          v = fmaxf(v, 0.0f) * wsc;
          dstH[(size_t)pos * DH + col] = f2bf(v);
        }
      }
  }
}

// ---------------------------------------------------------------------------
// Reduce masked partials + weight-folded b2 bias (SELECT, never multiply).
__global__ void reduce_kernel(float* __restrict__ dst,
                              const float* __restrict__ p0, const float* __restrict__ p1,
                              const float* __restrict__ p2, const float* __restrict__ p3,
                              const float* __restrict__ wgt,
                              const float* __restrict__ b2c, int camp) {
  const int b = blockIdx.x, t = threadIdx.x;
  const f32x4 wv = *(const f32x4*)(wgt + (size_t)b * NEXP + camp * 4);
  const size_t ro = (size_t)b * DOUT;
#pragma unroll
  for (int j = 0; j < 4; ++j) {
    const int i = j * 256 + t;
    float acc = wv[0] * b2c[i] + wv[1] * b2c[DOUT + i] +
                wv[2] * b2c[2 * DOUT + i] + wv[3] * b2c[3 * DOUT + i];
    acc += (wv[0] != 0.f) ? p0[ro + i] : 0.f;
    acc += (wv[1] != 0.f) ? p1[ro + i] : 0.f;
    acc += (wv[2] != 0.f) ? p2[ro + i] : 0.f;
    acc += (wv[3] != 0.f) ? p3[ro + i] : 0.f;
    dst[ro + i] = acc;
  }
}

// ---------------------------------------------------------------------------
// Fused camp-1 reduce + PH epilogue. Per row b:
//   g = select-sum(camp1 partials) + bias-fold; write out_g row;
//   d = out_a - g; ph_corr; write output row. All row-local -> deterministic.
__global__ void reduce_final_kernel(float* __restrict__ out,
                                    const float* __restrict__ p0,
                                    const float* __restrict__ p1,
                                    const float* __restrict__ p2,
                                    const float* __restrict__ p3,
                                    const float* __restrict__ wgt,
                                    const float* __restrict__ b2c,
                                    const float* __restrict__ alpha,
                                    const float* __restrict__ beta) {
  const int b = blockIdx.x, t = threadIdx.x;
  const f32x4 wv = *(const f32x4*)(wgt + (size_t)b * NEXP + 4);
  const size_t ro = (size_t)b * DOUT;
  const float* pa = out + (size_t)BATCH * DOUT + ro;
  float* pg = out + (size_t)2 * BATCH * DOUT + ro;
  float* po = out + ro;
  float g[4], d[4], s1 = 0.f, s2 = 0.f;
#pragma unroll
  for (int j = 0; j < 4; ++j) {
    const int i = j * 256 + t;
    float acc = wv[0] * b2c[i] + wv[1] * b2c[DOUT + i] +
                wv[2] * b2c[2 * DOUT + i] + wv[3] * b2c[3 * DOUT + i];
    acc += (wv[0] != 0.f) ? p0[ro + i] : 0.f;
    acc += (wv[1] != 0.f) ? p1[ro + i] : 0.f;
    acc += (wv[2] != 0.f) ? p2[ro + i] : 0.f;
    acc += (wv[3] != 0.f) ? p3[ro + i] : 0.f;
    g[j] = acc;
    d[j] = pa[i] - acc;
    s1 += d[j];
    s2 += d[j] * d[j];
  }
#pragma unroll
  for (int off = 32; off; off >>= 1) {
    s1 += __shfl_xor(s1, off);
    s2 += __shfl_xor(s2, off);
  }
  __shared__ float r1[4], r2[4];
  if ((t & 63) == 0) { r1[t >> 6] = s1; r2[t >> 6] = s2; }
  __syncthreads();
  s1 = r1[0] + r1[1] + r1[2] + r1[3];
  s2 = r2[0] + r2[1] + r2[2] + r2[3];
  const float mean = s1 * (1.f / DOUT);
  const float var = s2 * (1.f / DOUT) - mean * mean;  // population var
  const float dist = sqrtf(s2) * (1.f + var);
  const float zz = alpha[0] * dist + beta[0];
  const float corr = 2.f / (1.f + expf(-zz));
#pragma unroll
  for (int j = 0; j < 4; ++j) {
    const int i = j * 256 + t;
    pg[i] = g[j];
    po[i] = d[j] * corr;
  }
}

// ---------------------------------------------------------------------------
extern "C" void kernel_launch(void* const* d_in, const int* in_sizes, int n_in,
                              void* d_out, int out_size, void* d_ws, size_t ws_size,
                              hipStream_t stream) {
  const float* x   = (const float*)d_in[0];
  const float* gw  = (const float*)d_in[1];
  const float* gb  = (const float*)d_in[2];
  const float* w1  = (const float*)d_in[3];
  const float* b1  = (const float*)d_in[4];
  const float* w2  = (const float*)d_in[5];
  const float* b2  = (const float*)d_in[6];
  const float* pha = (const float*)d_in[7];
  const float* phb = (const float*)d_in[8];
  float* out = (float*)d_out;  // [output | out_a | out_g], each BATCH*DOUT f32
  float* out_a = out + (size_t)BATCH * DOUT;
  float* out_g = out + (size_t)2 * BATCH * DOUT;

  char* ws = (char*)d_ws;
  float* wgt  = (float*)ws;
  int* cnt    = (int*)(ws + 131072);
  u16* ridx   = (u16*)(ws + 135168);
  u16* Xe     = (u16*)(ws + 262144);
  constexpr size_t XE_BYTES  = (size_t)NEXP * HS_CAP * DIN * 2;   // 46.1 MB
  constexpr size_t W1T_BYTES = (size_t)NEXP * DH * DIN * 2;       // 64 MB
  constexpr size_t W2T_BYTES = (size_t)DOUT * 4 * DH * 2;         // 32 MB/camp
  constexpr size_t P_BYTES   = (size_t)BATCH * DOUT * 4;          // 16 MB
  constexpr size_t HS_E      = (size_t)HS_CAP * DH * 2;           // 23 MB/expert
  const size_t w1t_off = 262144 + XE_BYTES;
  u16* w1t = (u16*)(ws + w1t_off);

  // tier 1 (pipelined): w1t | w2t0 | w2t1 | P0 | P1 | Hs[8]  (~398.7 MB)
  const size_t pipe_need = w1t_off + W1T_BYTES + 2 * W2T_BYTES + 2 * P_BYTES + 8 * HS_E;
  // tier 2 (merged): w1t (->w2t after L1) | P0 | P1 | Hs[8]  (~331.6 MB)
  const size_t merged_need = w1t_off + W1T_BYTES + 2 * P_BYTES + 8 * HS_E;

  constexpr int NM = HS_CAP / 256;                 // 11
  constexpr int NN1 = DH / 256, NN2 = DOUT / 256;  // 16, 4

  // common prep
  gate_kernel<<<BATCH / 4, 256, 0, stream>>>(x, gw, gb, wgt);
  hipMemsetAsync(cnt, 0, NEXP * sizeof(int), stream);
  assign_kernel<<<BATCH / 256, 256, 0, stream>>>(wgt, cnt, ridx);
  gather_cvt<<<dim3(HS_CAP, NEXP), 128, 0, stream>>>(x, cnt, ridx, Xe);
  transpose_cvt<<<dim3(DH / 64, DIN / 64, NEXP), 256, 0, stream>>>(
      w1, w1t, DH, DIN, (size_t)DIN * DH, (size_t)4 * DH * DIN, (size_t)DH * DIN);

  if (ws_size >= pipe_need) {
    // ---- tier 1: co-scheduled [L2-camp0 || L1-camp1] ----
    u16* w2t0 = (u16*)(ws + w1t_off + W1T_BYTES);
    u16* w2t1 = (u16*)(ws + w1t_off + W1T_BYTES + W2T_BYTES);
    float* P0 = (float*)(ws + w1t_off + W1T_BYTES + 2 * W2T_BYTES);
    float* P1 = (float*)(ws + w1t_off + W1T_BYTES + 2 * W2T_BYTES + P_BYTES);
    u16* Hs   = (u16*)(ws + w1t_off + W1T_BYTES + 2 * W2T_BYTES + 2 * P_BYTES);
    Ptr4 pc0 = {{out_a, out, out_g, P0}};
    Ptr4 pc1 = {{out_g, out, P0, P1}};

    transpose_cvt<<<dim3(DOUT / 64, DH / 64, 4), 256, 0, stream>>>(
        w2, w2t0, DOUT, 4 * DH, (size_t)DH * DOUT, 0, (size_t)DH);
    transpose_cvt<<<dim3(DOUT / 64, DH / 64, 4), 256, 0, stream>>>(
        w2 + (size_t)4 * DH * DOUT, w2t1, DOUT, 4 * DH, (size_t)DH * DOUT, 0, (size_t)DH);

    // L1 camp0 (experts 0..3 -> Hs slots 0..3)
    gemm256<0><<<NM * NN1 * 4, 512, 0, stream>>>(
        Xe, DIN, w1t, DIN, DIN, Hs, pc0, wgt, b1, cnt, ridx, 0, NM, NN1);
    // combo: L2 camp0 (176 blocks, first) + L1 camp1 (704 blocks)
    gemm_combo<<<NM * NN2 * 4 + NM * NN1 * 4, 512, 0, stream>>>(
        Hs, w2t0, pc0, Xe, w1t, Hs, b1, wgt, cnt, ridx, NM * NN2 * 4);
    reduce_kernel<<<BATCH, 256, 0, stream>>>(out_a, out_a, out, out_g, P0, wgt, b2, 0);
    // L2 camp1 (Hs slots 4..7)
    gemm256<2><<<NM * NN2 * 4, 512, 0, stream>>>(
        Hs + (size_t)4 * HS_CAP * DH, DH, w2t1, 4 * DH, DH, nullptr, pc1,
        nullptr, nullptr, cnt, ridx, 1, NM, NN2);
    reduce_final_kernel<<<BATCH, 256, 0, stream>>>(out, out_g, out, P0, P1,
                                                   wgt, b2 + (size_t)4 * DOUT,
                                                   pha, phb);
  } else if (ws_size >= merged_need) {
    // ---- tier 2: round-11 merged (serial) ----
    float* P0 = (float*)(ws + w1t_off + W1T_BYTES);
    float* P1 = (float*)(ws + w1t_off + W1T_BYTES + P_BYTES);
    u16* Hs   = (u16*)(ws + w1t_off + W1T_BYTES + 2 * P_BYTES);
    u16* w2t0 = w1t;                               // recycled after merged L1
    u16* w2t1 = (u16*)((char*)w1t + W2T_BYTES);
    Ptr4 pc0 = {{out_a, out, out_g, P0}};
    Ptr4 pc1 = {{out_g, out, P0, P1}};

    gemm256<0><<<NM * NN1 * 8, 512, 0, stream>>>(
        Xe, DIN, w1t, DIN, DIN, Hs, pc0, wgt, b1, cnt, ridx, 0, NM, NN1);
    transpose_cvt<<<dim3(DOUT / 64, DH / 64, 4), 256, 0, stream>>>(
        w2, w2t0, DOUT, 4 * DH, (size_t)DH * DOUT, 0, (size_t)DH);
    transpose_cvt<<<dim3(DOUT / 64, DH / 64, 4), 256, 0, stream>>>(
        w2 + (size_t)4 * DH * DOUT, w2t1, DOUT, 4 * DH, (size_t)DH * DOUT, 0, (size_t)DH);
    gemm256<2><<<NM * NN2 * 4, 512, 0, stream>>>(
        Hs, DH, w2t0, 4 * DH, DH, nullptr, pc0, nullptr, nullptr, cnt, ridx, 0, NM, NN2);
    reduce_kernel<<<BATCH, 256, 0, stream>>>(out_a, out_a, out, out_g, P0, wgt, b2, 0);
    gemm256<2><<<NM * NN2 * 4, 512, 0, stream>>>(
        Hs + (size_t)4 * HS_CAP * DH, DH, w2t1, 4 * DH, DH, nullptr, pc1,
        nullptr, nullptr, cnt, ridx, 1, NM, NN2);
    reduce_final_kernel<<<BATCH, 256, 0, stream>>>(out, out_g, out, P0, P1,
                                                   wgt, b2 + (size_t)4 * DOUT,
                                                   pha, phb);
  } else {
    // ---- tier 3: round-9 sequential ----
    u16* w2t1 = w1t;                               // recycled after camp0 L1
    u16* w2t0 = (u16*)(ws + w1t_off + W1T_BYTES);
    float* P0 = (float*)(ws + w1t_off + W1T_BYTES + W2T_BYTES);
    float* P1 = (float*)(ws + w1t_off + W1T_BYTES + W2T_BYTES + P_BYTES);
    u16* Hs   = (u16*)(ws + w1t_off + W1T_BYTES + W2T_BYTES + 2 * P_BYTES);
    Ptr4 pc0 = {{out_a, out, out_g, P0}};
    Ptr4 pc1 = {{out_g, out, P0, P1}};

    transpose_cvt<<<dim3(DOUT / 64, DH / 64, 4), 256, 0, stream>>>(
        w2, w2t0, DOUT, 4 * DH, (size_t)DH * DOUT, 0, (size_t)DH);
    gemm256<0><<<NM * NN1 * 4, 512, 0, stream>>>(
        Xe, DIN, w1t, DIN, DIN, Hs, pc0, wgt, b1, cnt, ridx, 0, NM, NN1);
    transpose_cvt<<<dim3(DOUT / 64, DH / 64, 4), 256, 0, stream>>>(
        w2 + (size_t)4 * DH * DOUT, w2t1, DOUT, 4 * DH, (size_t)DH * DOUT, 0, (size_t)DH);
    gemm256<2><<<NM * NN2 * 4, 512, 0, stream>>>(
        Hs, DH, w2t0, 4 * DH, DH, nullptr, pc0, nullptr, nullptr, cnt, ridx, 0, NM, NN2);
    reduce_kernel<<<BATCH, 256, 0, stream>>>(out_a, out_a, out, out_g, P0, wgt, b2, 0);
    gemm256<0><<<NM * NN1 * 4, 512, 0, stream>>>(
        Xe, DIN, w1t, DIN, DIN, Hs, pc1, wgt, b1, cnt, ridx, 1, NM, NN1);
    gemm256<2><<<NM * NN2 * 4, 512, 0, stream>>>(
        Hs, DH, w2t1, 4 * DH, DH, nullptr, pc1, nullptr, nullptr, cnt, ridx, 1, NM, NN2);
    reduce_final_kernel<<<BATCH, 256, 0, stream>>>(out, out_g, out, P0, P1,
                                                   wgt, b2 + (size_t)4 * DOUT,
                                                   pha, phb);
  }
}